// Round 1
// 378.817 us; speedup vs baseline: 1.1691x; 1.1691x over previous
//
#include <hip/hip_runtime.h>
#include <hip/hip_bf16.h>

#define NF 128
#define NF2 256
#define NATOMS 100000
#define NGRAPH 128

#define MT 32
#define NBLK (NATOMS/MT)      // 3125
#define NTHR 512              // 8 waves

// blob layout per layer (bf16 elems): frags for 16x16x32 MFMA B-operand
#define OW1 0                 // 8ct x 4ks
#define OW2 16384
#define OA1 32768             // 8ct x 8ks
#define OA2 65536             // 16ct x 4ks (ct0-7 = s-half, ct8-15 = gate)
#define LAYER_SZ 98304

typedef __attribute__((ext_vector_type(8))) short bf16x8;
typedef __attribute__((ext_vector_type(4))) float f32x4;

static __device__ __forceinline__ float bf2f(__hip_bfloat16 x) { return __bfloat162float(x); }
static __device__ __forceinline__ __hip_bfloat16 f2bf(float x) { return __float2bfloat16(x); }
static __device__ __forceinline__ unsigned short f2bfu(float x) {
  __hip_bfloat16 h = __float2bfloat16(x);
  return *(unsigned short*)&h;
}
static __device__ __forceinline__ bf16x8 pack8(float4 lo, float4 hi) {
  union { unsigned short s[8]; bf16x8 v; } u;
  u.s[0]=f2bfu(lo.x); u.s[1]=f2bfu(lo.y); u.s[2]=f2bfu(lo.z); u.s[3]=f2bfu(lo.w);
  u.s[4]=f2bfu(hi.x); u.s[5]=f2bfu(hi.y); u.s[6]=f2bfu(hi.z); u.s[7]=f2bfu(hi.w);
  return u.v;
}

// Swizzled LDS tile: 16B granules, granule index XORed with (row&7).
static __device__ __forceinline__ bf16x8 ldfrag(const __hip_bfloat16* buf, int gr, int row, int gi) {
  return *(const bf16x8*)&buf[(row*gr + (gi ^ (row & 7)))*8];
}
static __device__ __forceinline__ void stb(__hip_bfloat16* buf, int gr, int row, int col, float v) {
  int gi = col >> 3, off = col & 7;
  buf[(row*gr + (gi ^ (row & 7)))*8 + off] = f2bf(v);
}
static __device__ __forceinline__ float ldb(const __hip_bfloat16* buf, int gr, int row, int col) {
  int gi = col >> 3, off = col & 7;
  return bf2f(buf[(row*gr + (gi ^ (row & 7)))*8 + off]);
}

// Pre-swizzle weights into per-MFMA B-fragment order for 16x16x32:
// blob[((ct*nks + ks)*64 + lane)*8 + j] = W[ks*32 + (lane>>4)*8 + j][ct*16 + (lane&15)]
__global__ __launch_bounds__(256)
void prep_weights(const float* __restrict__ w1, const float* __restrict__ w2,
                  const float* __restrict__ a1w, const float* __restrict__ a2w,
                  __hip_bfloat16* __restrict__ blob) {
  int gid = blockIdx.x * 256 + threadIdx.x;           // 24576 total
  int layer = gid / 12288;
  int r = gid - layer * 12288;
  const float* W; int N, nks, g; __hip_bfloat16* dst;
  if (r < 2048)      { W = w1  + layer*NF*NF;  N = NF;  nks = 4; dst = blob + layer*LAYER_SZ + OW1; g = r; }
  else if (r < 4096) { W = w2  + layer*NF*NF;  N = NF;  nks = 4; dst = blob + layer*LAYER_SZ + OW2; g = r - 2048; }
  else if (r < 8192) { W = a1w + layer*NF2*NF; N = NF;  nks = 8; dst = blob + layer*LAYER_SZ + OA1; g = r - 4096; }
  else               { W = a2w + layer*NF*NF2; N = NF2; nks = 4; dst = blob + layer*LAYER_SZ + OA2; g = r - 8192; }
  int lane = g & 63;
  int ks = (g >> 6) % nks;
  int ct = g / (64 * nks);
  int k0 = ks * 32 + ((lane >> 4) << 3);
  int n  = ct * 16 + (lane & 15);
  __hip_bfloat16* o = dst + (size_t)((ct * nks + ks) * 64 + lane) * 8;
  #pragma unroll
  for (int j = 0; j < 8; ++j) o[j] = f2bf(W[(size_t)(k0 + j) * N + n]);
}

// Fused kernel: 3125 blocks x 512 thr (8 waves), 48 KB LDS.
// launch_bounds(512, 4): 2 blocks/CU, VGPR cap 128/wave. The previous (512,6)
// capped VGPRs at ~80 -> Phase A's 64-dword working set (w1f+w2f+v1s+n2sq)
// spilled to scratch: ~410 MB writes + ~100 MB reads of parasitic HBM traffic
// (WRITE_SIZE was 409 MB == 256 B/thread exactly). 16 waves/CU is plenty to
// hide latency once the scratch round-trips are gone.
__global__ __launch_bounds__(NTHR, 4)
void fused_equiv(const float* __restrict__ s_g, const float* __restrict__ v_g,
                 const __hip_bfloat16* __restrict__ blob,
                 const float* __restrict__ a1b, const float* __restrict__ a2b,
                 const float* __restrict__ out_w, const float* __restrict__ out_b,
                 float* __restrict__ sc) {
  __shared__ __hip_bfloat16 vcur[3*MT*NF];   // 24 KB, 3 c-planes, swizzled, gr=16
  __shared__ __hip_bfloat16 hbuf[MT*NF2];    // 16 KB, [s | n2], gr=32
  __shared__ __hip_bfloat16 h1[MT*NF];       // 8 KB, gr=16

  const int tid  = threadIdx.x;
  const int wave = tid >> 6;                 // 0..7
  const int lane = tid & 63;
  const int l15  = lane & 15;
  const int quad = lane >> 4;
  const int a0   = blockIdx.x * MT;
  const int col  = wave*16 + l15;            // output column this lane owns

  // ---- stage: global fp32 -> bf16 swizzled LDS (coalesced 32B/lane) ----
  {
    int row = tid >> 4, gi = tid & 15;       // s: 1 granule/thread (512 total)
    const float* sp = s_g + (size_t)a0*NF + row*NF + gi*8;
    float4 lo = *(const float4*)sp;
    float4 hi = *(const float4*)(sp + 4);
    *(bf16x8*)&hbuf[(row*32 + (gi ^ (row & 7)))*8] = pack8(lo, hi);
    #pragma unroll
    for (int u = 0; u < 3; ++u) {            // v: 3 granules/thread (1536 total)
      int g = tid + u*512;
      int R = g >> 4, gi2 = g & 15;          // R = atom*3 + c
      int at = R / 3, c = R - 3*at;
      const float* vp = v_g + (size_t)a0*3*NF + R*NF + gi2*8;
      float4 vlo = *(const float4*)vp;
      float4 vhi = *(const float4*)(vp + 4);
      *(bf16x8*)&vcur[((c*MT + at)*16 + (gi2 ^ (at & 7)))*8] = pack8(vlo, vhi);
    }
  }
  __syncthreads();

  const float b1a  = a1b[col];
  const float b1g  = a1b[NF + col];
  const float b2s  = a2b[col];
  const float b2g  = a2b[NF + col];
  const float b2s2 = a2b[2*NF + col];

  // ================= Layer 1 =================
  // ---- Phase A: v @ [w1|w2] per c-plane; v1, n2 from same-lane accs ----
  f32x4 v1s[3][2]; float n2sq[2][4];
  {
    const __hip_bfloat16* lb = blob;
    bf16x8 w1f[4], w2f[4];
    #pragma unroll
    for (int ks = 0; ks < 4; ++ks) {
      w1f[ks] = *(const bf16x8*)&lb[OW1 + ((size_t)(wave*4 + ks)*64 + lane)*8];
      w2f[ks] = *(const bf16x8*)&lb[OW2 + ((size_t)(wave*4 + ks)*64 + lane)*8];
    }
    #pragma unroll
    for (int rt = 0; rt < 2; ++rt) { n2sq[rt][0]=0.f; n2sq[rt][1]=0.f; n2sq[rt][2]=0.f; n2sq[rt][3]=0.f; }
    #pragma unroll
    for (int c = 0; c < 3; ++c) {
      const __hip_bfloat16* vp = vcur + c*MT*NF;
      #pragma unroll
      for (int rt = 0; rt < 2; ++rt) {
        int row = rt*16 + l15;
        f32x4 acc1 = {0.f,0.f,0.f,0.f}, acc2 = {0.f,0.f,0.f,0.f};
        #pragma unroll
        for (int ks = 0; ks < 4; ++ks) {
          bf16x8 af = ldfrag(vp, 16, row, ks*4 + quad);
          acc1 = __builtin_amdgcn_mfma_f32_16x16x32_bf16(af, w1f[ks], acc1, 0, 0, 0);
          acc2 = __builtin_amdgcn_mfma_f32_16x16x32_bf16(af, w2f[ks], acc2, 0, 0, 0);
        }
        v1s[c][rt] = acc1;
        #pragma unroll
        for (int i = 0; i < 4; ++i) n2sq[rt][i] += acc2[i]*acc2[i];
      }
    }
  }
  __syncthreads();   // all reads of vcur done -> safe to overwrite with v1
  {
    #pragma unroll
    for (int rt = 0; rt < 2; ++rt)
      #pragma unroll
      for (int i = 0; i < 4; ++i) {
        int row = rt*16 + quad*4 + i;
        stb(hbuf, 32, row, NF + col, sqrtf(n2sq[rt][i]));
        stb(vcur,           16, row, col, v1s[0][rt][i]);
        stb(vcur +   MT*NF, 16, row, col, v1s[1][rt][i]);
        stb(vcur + 2*MT*NF, 16, row, col, v1s[2][rt][i]);
      }
  }
  __syncthreads();

  // ---- Phase B: [s|n2] @ a1w + bias, silu -> h1 ----
  {
    const __hip_bfloat16* lb = blob;
    bf16x8 a1f[8];
    #pragma unroll
    for (int ks = 0; ks < 8; ++ks)
      a1f[ks] = *(const bf16x8*)&lb[OA1 + ((size_t)(wave*8 + ks)*64 + lane)*8];
    #pragma unroll
    for (int rt = 0; rt < 2; ++rt) {
      int row = rt*16 + l15;
      f32x4 acc = {0.f,0.f,0.f,0.f};
      #pragma unroll
      for (int ks = 0; ks < 8; ++ks) {
        bf16x8 af = ldfrag(hbuf, 32, row, ks*4 + quad);
        acc = __builtin_amdgcn_mfma_f32_16x16x32_bf16(af, a1f[ks], acc, 0, 0, 0);
      }
      #pragma unroll
      for (int i = 0; i < 4; ++i) {
        float x = acc[i] + b1a;
        stb(h1, 16, rt*16 + quad*4 + i, col, x / (1.0f + __expf(-x)));
      }
    }
  }
  __syncthreads();

  // ---- Phase C: h1 @ a2w -> s1 (hbuf) + gate * v1 (vcur, same-lane cells) ----
  {
    const __hip_bfloat16* lb = blob;
    bf16x8 asf[4], agf[4];
    #pragma unroll
    for (int ks = 0; ks < 4; ++ks) {
      asf[ks] = *(const bf16x8*)&lb[OA2 + ((size_t)(wave*4 + ks)*64 + lane)*8];
      agf[ks] = *(const bf16x8*)&lb[OA2 + ((size_t)((wave+8)*4 + ks)*64 + lane)*8];
    }
    #pragma unroll
    for (int rt = 0; rt < 2; ++rt) {
      int row = rt*16 + l15;
      f32x4 hs = {0.f,0.f,0.f,0.f}, hg = {0.f,0.f,0.f,0.f};
      #pragma unroll
      for (int ks = 0; ks < 4; ++ks) {
        bf16x8 af = ldfrag(h1, 16, row, ks*4 + quad);
        hs = __builtin_amdgcn_mfma_f32_16x16x32_bf16(af, asf[ks], hs, 0, 0, 0);
        hg = __builtin_amdgcn_mfma_f32_16x16x32_bf16(af, agf[ks], hg, 0, 0, 0);
      }
      #pragma unroll
      for (int i = 0; i < 4; ++i) {
        int r = rt*16 + quad*4 + i;
        stb(hbuf, 32, r, col, hs[i] + b2s);
        float g = hg[i] + b2g;
        stb(vcur,           16, r, col, g * ldb(vcur,           16, r, col));
        stb(vcur +   MT*NF, 16, r, col, g * ldb(vcur +   MT*NF, 16, r, col));
        stb(vcur + 2*MT*NF, 16, r, col, g * ldb(vcur + 2*MT*NF, 16, r, col));
      }
    }
  }
  __syncthreads();

  // ================= Layer 2 (v1/gate of last layer unused) =================
  // ---- Phase A': v' @ w2 -> n2 ----
  {
    const __hip_bfloat16* lb = blob + LAYER_SZ;
    bf16x8 w2f[4];
    #pragma unroll
    for (int ks = 0; ks < 4; ++ks)
      w2f[ks] = *(const bf16x8*)&lb[OW2 + ((size_t)(wave*4 + ks)*64 + lane)*8];
    #pragma unroll
    for (int rt = 0; rt < 2; ++rt) {
      int row = rt*16 + l15;
      float nq[4] = {0.f,0.f,0.f,0.f};
      #pragma unroll
      for (int c = 0; c < 3; ++c) {
        const __hip_bfloat16* vp = vcur + c*MT*NF;
        f32x4 acc = {0.f,0.f,0.f,0.f};
        #pragma unroll
        for (int ks = 0; ks < 4; ++ks) {
          bf16x8 af = ldfrag(vp, 16, row, ks*4 + quad);
          acc = __builtin_amdgcn_mfma_f32_16x16x32_bf16(af, w2f[ks], acc, 0, 0, 0);
        }
        #pragma unroll
        for (int i = 0; i < 4; ++i) nq[i] += acc[i]*acc[i];
      }
      #pragma unroll
      for (int i = 0; i < 4; ++i)
        stb(hbuf, 32, rt*16 + quad*4 + i, NF + col, sqrtf(nq[i]));
    }
  }
  __syncthreads();

  // ---- Phase B' ----
  {
    const __hip_bfloat16* lb = blob + LAYER_SZ;
    bf16x8 a1f[8];
    #pragma unroll
    for (int ks = 0; ks < 8; ++ks)
      a1f[ks] = *(const bf16x8*)&lb[OA1 + ((size_t)(wave*8 + ks)*64 + lane)*8];
    #pragma unroll
    for (int rt = 0; rt < 2; ++rt) {
      int row = rt*16 + l15;
      f32x4 acc = {0.f,0.f,0.f,0.f};
      #pragma unroll
      for (int ks = 0; ks < 8; ++ks) {
        bf16x8 af = ldfrag(hbuf, 32, row, ks*4 + quad);
        acc = __builtin_amdgcn_mfma_f32_16x16x32_bf16(af, a1f[ks], acc, 0, 0, 0);
      }
      #pragma unroll
      for (int i = 0; i < 4; ++i) {
        float x = acc[i] + b1g;
        stb(h1, 16, rt*16 + quad*4 + i, col, x / (1.0f + __expf(-x)));
      }
    }
  }
  __syncthreads();

  // ---- Phase C': s2 only -> hbuf s-half ----
  {
    const __hip_bfloat16* lb = blob + LAYER_SZ;
    bf16x8 asf[4];
    #pragma unroll
    for (int ks = 0; ks < 4; ++ks)
      asf[ks] = *(const bf16x8*)&lb[OA2 + ((size_t)(wave*4 + ks)*64 + lane)*8];
    #pragma unroll
    for (int rt = 0; rt < 2; ++rt) {
      int row = rt*16 + l15;
      f32x4 hs = {0.f,0.f,0.f,0.f};
      #pragma unroll
      for (int ks = 0; ks < 4; ++ks) {
        bf16x8 af = ldfrag(h1, 16, row, ks*4 + quad);
        hs = __builtin_amdgcn_mfma_f32_16x16x32_bf16(af, asf[ks], hs, 0, 0, 0);
      }
      #pragma unroll
      for (int i = 0; i < 4; ++i)
        stb(hbuf, 32, rt*16 + quad*4 + i, col, hs[i] + b2s2);
    }
  }
  __syncthreads();

  // ---- head: sc[atom] = dot(s2, out_w) + out_b ----
  {
    int a   = tid >> 4;        // 32 atoms x 16 threads
    int sub = tid & 15;
    float p = 0.f;
    #pragma unroll
    for (int j = 0; j < 8; ++j) {
      int f = sub*8 + j;
      p += ldb(hbuf, 32, a, f) * out_w[f];
    }
    p += __shfl_down(p, 8, 16);
    p += __shfl_down(p, 4, 16);
    p += __shfl_down(p, 2, 16);
    p += __shfl_down(p, 1, 16);
    if (sub == 0) sc[a0 + a] = p + out_b[0];
  }
}

// Stage 1: partials over 16 aligned chunks per graph (2048 blocks, float4 loads)
#define CHUNK 6256   // 16B-aligned chunk (6256*4 bytes); last chunk = 6160
__global__ __launch_bounds__(256)
void reduce_partial(const float* __restrict__ mask, const float* __restrict__ sc,
                    float* __restrict__ partial) {
  int b  = blockIdx.x >> 4;
  int ch = blockIdx.x & 15;
  int n0 = ch * CHUNK;
  int n1 = n0 + CHUNK; if (n1 > NATOMS) n1 = NATOMS;
  const float4* m4 = (const float4*)(mask + (size_t)b * NATOMS + n0);
  const float4* s4 = (const float4*)(sc + n0);
  int nq = (n1 - n0) >> 2;
  float acc = 0.f;
  for (int i = threadIdx.x; i < nq; i += 256) {
    float4 m = m4[i], s = s4[i];
    acc += m.x*s.x + m.y*s.y + m.z*s.z + m.w*s.w;
  }
  #pragma unroll
  for (int d = 32; d > 0; d >>= 1) acc += __shfl_down(acc, d, 64);
  __shared__ float red[4];
  if ((threadIdx.x & 63) == 0) red[threadIdx.x >> 6] = acc;
  __syncthreads();
  if (threadIdx.x == 0) partial[blockIdx.x] = red[0] + red[1] + red[2] + red[3];
}

__global__ void reduce_final(const float* __restrict__ partial, float* __restrict__ out) {
  int b = threadIdx.x;
  if (b < NGRAPH) {
    float s = 0.f;
    #pragma unroll
    for (int k = 0; k < 16; ++k) s += partial[b*16 + k];
    out[b] = s;
  }
}

extern "C" void kernel_launch(void* const* d_in, const int* in_sizes, int n_in,
                              void* d_out, int out_size, void* d_ws, size_t ws_size,
                              hipStream_t stream) {
  const float* s    = (const float*)d_in[0];
  const float* v    = (const float*)d_in[1];
  // d_in[2] = r, unused
  const float* mask = (const float*)d_in[3];
  const float* w1   = (const float*)d_in[4];
  const float* w2   = (const float*)d_in[5];
  const float* a1w  = (const float*)d_in[6];
  const float* a1b  = (const float*)d_in[7];
  const float* a2w  = (const float*)d_in[8];
  const float* a2b  = (const float*)d_in[9];
  const float* outw = (const float*)d_in[10];
  const float* outb = (const float*)d_in[11];

  char* ws = (char*)d_ws;
  __hip_bfloat16* blob = (__hip_bfloat16*)ws;                      // 384 KB
  float* sc      = (float*)(ws + (size_t)2*LAYER_SZ*2);            // 400 KB
  float* partial = (float*)(ws + (size_t)2*LAYER_SZ*2 + NATOMS*4); // 8 KB

  prep_weights<<<96, 256, 0, stream>>>(w1, w2, a1w, a2w, blob);
  fused_equiv<<<NBLK, NTHR, 0, stream>>>(s, v, blob, a1b, a2b, outw, outb, sc);
  reduce_partial<<<NGRAPH*16, 256, 0, stream>>>(mask, sc, partial);
  reduce_final<<<1, 128, 0, stream>>>(partial, (float*)d_out);
}

// Round 2
// 364.152 us; speedup vs baseline: 1.2162x; 1.0403x over previous
//
#include <hip/hip_runtime.h>
#include <hip/hip_bf16.h>

#define NF 128
#define NF2 256
#define NATOMS 100000
#define NGRAPH 128

#define MT 32
#define NBLK (NATOMS/MT)      // 3125
#define NTHR 512              // 8 waves

// blob layout per layer (bf16 elems): frags for 16x16x32 MFMA B-operand
#define OW1 0                 // 8ct x 4ks
#define OW2 16384
#define OA1 32768             // 8ct x 8ks
#define OA2 65536             // 16ct x 4ks (ct0-7 = s-half, ct8-15 = gate)
#define LAYER_SZ 98304

typedef __attribute__((ext_vector_type(8))) short bf16x8;
typedef __attribute__((ext_vector_type(4))) float f32x4;

static __device__ __forceinline__ float bf2f(__hip_bfloat16 x) { return __bfloat162float(x); }
static __device__ __forceinline__ __hip_bfloat16 f2bf(float x) { return __float2bfloat16(x); }
static __device__ __forceinline__ unsigned short f2bfu(float x) {
  __hip_bfloat16 h = __float2bfloat16(x);
  return *(unsigned short*)&h;
}
static __device__ __forceinline__ bf16x8 pack8(float4 lo, float4 hi) {
  union { unsigned short s[8]; bf16x8 v; } u;
  u.s[0]=f2bfu(lo.x); u.s[1]=f2bfu(lo.y); u.s[2]=f2bfu(lo.z); u.s[3]=f2bfu(lo.w);
  u.s[4]=f2bfu(hi.x); u.s[5]=f2bfu(hi.y); u.s[6]=f2bfu(hi.z); u.s[7]=f2bfu(hi.w);
  return u.v;
}

// Swizzled LDS tile: 16B granules, granule index XORed with (row&7).
static __device__ __forceinline__ bf16x8 ldfrag(const __hip_bfloat16* buf, int gr, int row, int gi) {
  return *(const bf16x8*)&buf[(row*gr + (gi ^ (row & 7)))*8];
}
static __device__ __forceinline__ void stb(__hip_bfloat16* buf, int gr, int row, int col, float v) {
  int gi = col >> 3, off = col & 7;
  buf[(row*gr + (gi ^ (row & 7)))*8 + off] = f2bf(v);
}
static __device__ __forceinline__ float ldb(const __hip_bfloat16* buf, int gr, int row, int col) {
  int gi = col >> 3, off = col & 7;
  return bf2f(buf[(row*gr + (gi ^ (row & 7)))*8 + off]);
}

// Pre-swizzle weights into per-MFMA B-fragment order for 16x16x32:
// blob[((ct*nks + ks)*64 + lane)*8 + j] = W[ks*32 + (lane>>4)*8 + j][ct*16 + (lane&15)]
__global__ __launch_bounds__(256)
void prep_weights(const float* __restrict__ w1, const float* __restrict__ w2,
                  const float* __restrict__ a1w, const float* __restrict__ a2w,
                  __hip_bfloat16* __restrict__ blob) {
  int gid = blockIdx.x * 256 + threadIdx.x;           // 24576 total
  int layer = gid / 12288;
  int r = gid - layer * 12288;
  const float* W; int N, nks, g; __hip_bfloat16* dst;
  if (r < 2048)      { W = w1  + layer*NF*NF;  N = NF;  nks = 4; dst = blob + layer*LAYER_SZ + OW1; g = r; }
  else if (r < 4096) { W = w2  + layer*NF*NF;  N = NF;  nks = 4; dst = blob + layer*LAYER_SZ + OW2; g = r - 2048; }
  else if (r < 8192) { W = a1w + layer*NF2*NF; N = NF;  nks = 8; dst = blob + layer*LAYER_SZ + OA1; g = r - 4096; }
  else               { W = a2w + layer*NF*NF2; N = NF2; nks = 4; dst = blob + layer*LAYER_SZ + OA2; g = r - 8192; }
  int lane = g & 63;
  int ks = (g >> 6) % nks;
  int ct = g / (64 * nks);
  int k0 = ks * 32 + ((lane >> 4) << 3);
  int n  = ct * 16 + (lane & 15);
  __hip_bfloat16* o = dst + (size_t)((ct * nks + ks) * 64 + lane) * 8;
  #pragma unroll
  for (int j = 0; j < 8; ++j) o[j] = f2bf(W[(size_t)(k0 + j) * N + n]);
}

// Fused kernel: 3125 blocks x 512 thr (8 waves), 72 KB LDS, 2 blocks/CU.
// R1 post-mortem: VGPR allocator was pegged at the 128 cap and still spilled
// 16 dwords/lane (WRITE_SIZE 100 MB == 64 B/thread). Demand ~144 came from
// v1s[3][2] (24 regs) held across a barrier plus w1f/w2f (32) plus hoisted
// next-phase fragments. Fix: write v1 through to a dedicated LDS buffer
// (v1lds) inside Phase A -> v1s eliminated, one barrier removed. +24 KB LDS
// still fits 2 blocks/CU (144 KB <= 160 KB).
__global__ __launch_bounds__(NTHR, 4)
void fused_equiv(const float* __restrict__ s_g, const float* __restrict__ v_g,
                 const __hip_bfloat16* __restrict__ blob,
                 const float* __restrict__ a1b, const float* __restrict__ a2b,
                 const float* __restrict__ out_w, const float* __restrict__ out_b,
                 float* __restrict__ sc) {
  __shared__ __hip_bfloat16 vcur[3*MT*NF];   // 24 KB, staged v, swizzled, gr=16
  __shared__ __hip_bfloat16 v1lds[3*MT*NF];  // 24 KB, v1 then gated v1
  __shared__ __hip_bfloat16 hbuf[MT*NF2];    // 16 KB, [s | n2], gr=32
  __shared__ __hip_bfloat16 h1[MT*NF];       // 8 KB, gr=16

  const int tid  = threadIdx.x;
  const int wave = tid >> 6;                 // 0..7
  const int lane = tid & 63;
  const int l15  = lane & 15;
  const int quad = lane >> 4;
  const int a0   = blockIdx.x * MT;
  const int col  = wave*16 + l15;            // output column this lane owns

  // ---- stage: global fp32 -> bf16 swizzled LDS (coalesced 32B/lane) ----
  {
    int row = tid >> 4, gi = tid & 15;       // s: 1 granule/thread (512 total)
    const float* sp = s_g + (size_t)a0*NF + row*NF + gi*8;
    float4 lo = *(const float4*)sp;
    float4 hi = *(const float4*)(sp + 4);
    *(bf16x8*)&hbuf[(row*32 + (gi ^ (row & 7)))*8] = pack8(lo, hi);
    #pragma unroll
    for (int u = 0; u < 3; ++u) {            // v: 3 granules/thread (1536 total)
      int g = tid + u*512;
      int R = g >> 4, gi2 = g & 15;          // R = atom*3 + c
      int at = R / 3, c = R - 3*at;
      const float* vp = v_g + (size_t)a0*3*NF + R*NF + gi2*8;
      float4 vlo = *(const float4*)vp;
      float4 vhi = *(const float4*)(vp + 4);
      *(bf16x8*)&vcur[((c*MT + at)*16 + (gi2 ^ (at & 7)))*8] = pack8(vlo, vhi);
    }
  }
  __syncthreads();

  const float b1a  = a1b[col];
  const float b1g  = a1b[NF + col];
  const float b2s  = a2b[col];
  const float b2g  = a2b[NF + col];
  const float b2s2 = a2b[2*NF + col];

  // ================= Layer 1 =================
  // ---- Phase A: v @ [w1|w2]; v1 written through to v1lds, n2 to hbuf ----
  {
    const __hip_bfloat16* lb = blob;
    bf16x8 w1f[4], w2f[4];
    #pragma unroll
    for (int ks = 0; ks < 4; ++ks) {
      w1f[ks] = *(const bf16x8*)&lb[OW1 + ((size_t)(wave*4 + ks)*64 + lane)*8];
      w2f[ks] = *(const bf16x8*)&lb[OW2 + ((size_t)(wave*4 + ks)*64 + lane)*8];
    }
    float n2sq[2][4];
    #pragma unroll
    for (int rt = 0; rt < 2; ++rt) { n2sq[rt][0]=0.f; n2sq[rt][1]=0.f; n2sq[rt][2]=0.f; n2sq[rt][3]=0.f; }
    #pragma unroll
    for (int c = 0; c < 3; ++c) {
      const __hip_bfloat16* vp = vcur + c*MT*NF;
      __hip_bfloat16* op = v1lds + c*MT*NF;
      #pragma unroll
      for (int rt = 0; rt < 2; ++rt) {
        int row = rt*16 + l15;
        f32x4 acc1 = {0.f,0.f,0.f,0.f}, acc2 = {0.f,0.f,0.f,0.f};
        #pragma unroll
        for (int ks = 0; ks < 4; ++ks) {
          bf16x8 af = ldfrag(vp, 16, row, ks*4 + quad);
          acc1 = __builtin_amdgcn_mfma_f32_16x16x32_bf16(af, w1f[ks], acc1, 0, 0, 0);
          acc2 = __builtin_amdgcn_mfma_f32_16x16x32_bf16(af, w2f[ks], acc2, 0, 0, 0);
        }
        #pragma unroll
        for (int i = 0; i < 4; ++i) {
          stb(op, 16, rt*16 + quad*4 + i, col, acc1[i]);   // v1 write-through
          n2sq[rt][i] += acc2[i]*acc2[i];
        }
      }
    }
    #pragma unroll
    for (int rt = 0; rt < 2; ++rt)
      #pragma unroll
      for (int i = 0; i < 4; ++i)
        stb(hbuf, 32, rt*16 + quad*4 + i, NF + col, sqrtf(n2sq[rt][i]));
  }
  __syncthreads();

  // ---- Phase B: [s|n2] @ a1w + bias, silu -> h1 ----
  {
    const __hip_bfloat16* lb = blob;
    bf16x8 a1f[8];
    #pragma unroll
    for (int ks = 0; ks < 8; ++ks)
      a1f[ks] = *(const bf16x8*)&lb[OA1 + ((size_t)(wave*8 + ks)*64 + lane)*8];
    #pragma unroll
    for (int rt = 0; rt < 2; ++rt) {
      int row = rt*16 + l15;
      f32x4 acc = {0.f,0.f,0.f,0.f};
      #pragma unroll
      for (int ks = 0; ks < 8; ++ks) {
        bf16x8 af = ldfrag(hbuf, 32, row, ks*4 + quad);
        acc = __builtin_amdgcn_mfma_f32_16x16x32_bf16(af, a1f[ks], acc, 0, 0, 0);
      }
      #pragma unroll
      for (int i = 0; i < 4; ++i) {
        float x = acc[i] + b1a;
        stb(h1, 16, rt*16 + quad*4 + i, col, x / (1.0f + __expf(-x)));
      }
    }
  }
  __syncthreads();

  // ---- Phase C: h1 @ a2w -> s1 (hbuf) + gate * v1 (v1lds in place) ----
  {
    const __hip_bfloat16* lb = blob;
    bf16x8 asf[4], agf[4];
    #pragma unroll
    for (int ks = 0; ks < 4; ++ks) {
      asf[ks] = *(const bf16x8*)&lb[OA2 + ((size_t)(wave*4 + ks)*64 + lane)*8];
      agf[ks] = *(const bf16x8*)&lb[OA2 + ((size_t)((wave+8)*4 + ks)*64 + lane)*8];
    }
    #pragma unroll
    for (int rt = 0; rt < 2; ++rt) {
      int row = rt*16 + l15;
      f32x4 hs = {0.f,0.f,0.f,0.f}, hg = {0.f,0.f,0.f,0.f};
      #pragma unroll
      for (int ks = 0; ks < 4; ++ks) {
        bf16x8 af = ldfrag(h1, 16, row, ks*4 + quad);
        hs = __builtin_amdgcn_mfma_f32_16x16x32_bf16(af, asf[ks], hs, 0, 0, 0);
        hg = __builtin_amdgcn_mfma_f32_16x16x32_bf16(af, agf[ks], hg, 0, 0, 0);
      }
      #pragma unroll
      for (int i = 0; i < 4; ++i) {
        int r = rt*16 + quad*4 + i;
        stb(hbuf, 32, r, col, hs[i] + b2s);
        float g = hg[i] + b2g;
        stb(v1lds,           16, r, col, g * ldb(v1lds,           16, r, col));
        stb(v1lds +   MT*NF, 16, r, col, g * ldb(v1lds +   MT*NF, 16, r, col));
        stb(v1lds + 2*MT*NF, 16, r, col, g * ldb(v1lds + 2*MT*NF, 16, r, col));
      }
    }
  }
  __syncthreads();

  // ================= Layer 2 (v1/gate of last layer unused) =================
  // ---- Phase A': v' @ w2 -> n2 ----
  {
    const __hip_bfloat16* lb = blob + LAYER_SZ;
    bf16x8 w2f[4];
    #pragma unroll
    for (int ks = 0; ks < 4; ++ks)
      w2f[ks] = *(const bf16x8*)&lb[OW2 + ((size_t)(wave*4 + ks)*64 + lane)*8];
    #pragma unroll
    for (int rt = 0; rt < 2; ++rt) {
      int row = rt*16 + l15;
      float nq[4] = {0.f,0.f,0.f,0.f};
      #pragma unroll
      for (int c = 0; c < 3; ++c) {
        const __hip_bfloat16* vp = v1lds + c*MT*NF;
        f32x4 acc = {0.f,0.f,0.f,0.f};
        #pragma unroll
        for (int ks = 0; ks < 4; ++ks) {
          bf16x8 af = ldfrag(vp, 16, row, ks*4 + quad);
          acc = __builtin_amdgcn_mfma_f32_16x16x32_bf16(af, w2f[ks], acc, 0, 0, 0);
        }
        #pragma unroll
        for (int i = 0; i < 4; ++i) nq[i] += acc[i]*acc[i];
      }
      #pragma unroll
      for (int i = 0; i < 4; ++i)
        stb(hbuf, 32, rt*16 + quad*4 + i, NF + col, sqrtf(nq[i]));
    }
  }
  __syncthreads();

  // ---- Phase B' ----
  {
    const __hip_bfloat16* lb = blob + LAYER_SZ;
    bf16x8 a1f[8];
    #pragma unroll
    for (int ks = 0; ks < 8; ++ks)
      a1f[ks] = *(const bf16x8*)&lb[OA1 + ((size_t)(wave*8 + ks)*64 + lane)*8];
    #pragma unroll
    for (int rt = 0; rt < 2; ++rt) {
      int row = rt*16 + l15;
      f32x4 acc = {0.f,0.f,0.f,0.f};
      #pragma unroll
      for (int ks = 0; ks < 8; ++ks) {
        bf16x8 af = ldfrag(hbuf, 32, row, ks*4 + quad);
        acc = __builtin_amdgcn_mfma_f32_16x16x32_bf16(af, a1f[ks], acc, 0, 0, 0);
      }
      #pragma unroll
      for (int i = 0; i < 4; ++i) {
        float x = acc[i] + b1g;
        stb(h1, 16, rt*16 + quad*4 + i, col, x / (1.0f + __expf(-x)));
      }
    }
  }
  __syncthreads();

  // ---- Phase C': s2 only -> hbuf s-half ----
  {
    const __hip_bfloat16* lb = blob + LAYER_SZ;
    bf16x8 asf[4];
    #pragma unroll
    for (int ks = 0; ks < 4; ++ks)
      asf[ks] = *(const bf16x8*)&lb[OA2 + ((size_t)(wave*4 + ks)*64 + lane)*8];
    #pragma unroll
    for (int rt = 0; rt < 2; ++rt) {
      int row = rt*16 + l15;
      f32x4 hs = {0.f,0.f,0.f,0.f};
      #pragma unroll
      for (int ks = 0; ks < 4; ++ks) {
        bf16x8 af = ldfrag(h1, 16, row, ks*4 + quad);
        hs = __builtin_amdgcn_mfma_f32_16x16x32_bf16(af, asf[ks], hs, 0, 0, 0);
      }
      #pragma unroll
      for (int i = 0; i < 4; ++i)
        stb(hbuf, 32, rt*16 + quad*4 + i, col, hs[i] + b2s2);
    }
  }
  __syncthreads();

  // ---- head: sc[atom] = dot(s2, out_w) + out_b ----
  {
    int a   = tid >> 4;        // 32 atoms x 16 threads
    int sub = tid & 15;
    float p = 0.f;
    #pragma unroll
    for (int j = 0; j < 8; ++j) {
      int f = sub*8 + j;
      p += ldb(hbuf, 32, a, f) * out_w[f];
    }
    p += __shfl_down(p, 8, 16);
    p += __shfl_down(p, 4, 16);
    p += __shfl_down(p, 2, 16);
    p += __shfl_down(p, 1, 16);
    if (sub == 0) sc[a0 + a] = p + out_b[0];
  }
}

// Stage 1: partials over 16 aligned chunks per graph (2048 blocks, float4 loads)
#define CHUNK 6256   // 16B-aligned chunk (6256*4 bytes); last chunk = 6160
__global__ __launch_bounds__(256)
void reduce_partial(const float* __restrict__ mask, const float* __restrict__ sc,
                    float* __restrict__ partial) {
  int b  = blockIdx.x >> 4;
  int ch = blockIdx.x & 15;
  int n0 = ch * CHUNK;
  int n1 = n0 + CHUNK; if (n1 > NATOMS) n1 = NATOMS;
  const float4* m4 = (const float4*)(mask + (size_t)b * NATOMS + n0);
  const float4* s4 = (const float4*)(sc + n0);
  int nq = (n1 - n0) >> 2;
  float acc = 0.f;
  for (int i = threadIdx.x; i < nq; i += 256) {
    float4 m = m4[i], s = s4[i];
    acc += m.x*s.x + m.y*s.y + m.z*s.z + m.w*s.w;
  }
  #pragma unroll
  for (int d = 32; d > 0; d >>= 1) acc += __shfl_down(acc, d, 64);
  __shared__ float red[4];
  if ((threadIdx.x & 63) == 0) red[threadIdx.x >> 6] = acc;
  __syncthreads();
  if (threadIdx.x == 0) partial[blockIdx.x] = red[0] + red[1] + red[2] + red[3];
}

__global__ void reduce_final(const float* __restrict__ partial, float* __restrict__ out) {
  int b = threadIdx.x;
  if (b < NGRAPH) {
    float s = 0.f;
    #pragma unroll
    for (int k = 0; k < 16; ++k) s += partial[b*16 + k];
    out[b] = s;
  }
}

extern "C" void kernel_launch(void* const* d_in, const int* in_sizes, int n_in,
                              void* d_out, int out_size, void* d_ws, size_t ws_size,
                              hipStream_t stream) {
  const float* s    = (const float*)d_in[0];
  const float* v    = (const float*)d_in[1];
  // d_in[2] = r, unused
  const float* mask = (const float*)d_in[3];
  const float* w1   = (const float*)d_in[4];
  const float* w2   = (const float*)d_in[5];
  const float* a1w  = (const float*)d_in[6];
  const float* a1b  = (const float*)d_in[7];
  const float* a2w  = (const float*)d_in[8];
  const float* a2b  = (const float*)d_in[9];
  const float* outw = (const float*)d_in[10];
  const float* outb = (const float*)d_in[11];

  char* ws = (char*)d_ws;
  __hip_bfloat16* blob = (__hip_bfloat16*)ws;                      // 384 KB
  float* sc      = (float*)(ws + (size_t)2*LAYER_SZ*2);            // 400 KB
  float* partial = (float*)(ws + (size_t)2*LAYER_SZ*2 + NATOMS*4); // 8 KB

  prep_weights<<<96, 256, 0, stream>>>(w1, w2, a1w, a2w, blob);
  fused_equiv<<<NBLK, NTHR, 0, stream>>>(s, v, blob, a1b, a2b, outw, outb, sc);
  reduce_partial<<<NGRAPH*16, 256, 0, stream>>>(mask, sc, partial);
  reduce_final<<<1, 128, 0, stream>>>(partial, (float*)d_out);
}

// Round 3
// 361.872 us; speedup vs baseline: 1.2238x; 1.0063x over previous
//
#include <hip/hip_runtime.h>
#include <hip/hip_bf16.h>

#define NF 128
#define NF2 256
#define NATOMS 100000
#define NGRAPH 128

#define MT 32
#define NBLK (NATOMS/MT)      // 3125
#define NTHR 512              // 8 waves

// blob layout per layer (bf16 elems): frags for 16x16x32 MFMA B-operand
#define OW1 0                 // 8ct x 4ks
#define OW2 16384
#define OA1 32768             // 8ct x 8ks
#define OA2 65536             // 16ct x 4ks (ct0-7 = s-half, ct8-15 = gate)
#define LAYER_SZ 98304

typedef __attribute__((ext_vector_type(8))) short bf16x8;
typedef __attribute__((ext_vector_type(4))) float f32x4;

static __device__ __forceinline__ float bf2f(__hip_bfloat16 x) { return __bfloat162float(x); }
static __device__ __forceinline__ __hip_bfloat16 f2bf(float x) { return __float2bfloat16(x); }
static __device__ __forceinline__ unsigned short f2bfu(float x) {
  __hip_bfloat16 h = __float2bfloat16(x);
  return *(unsigned short*)&h;
}
static __device__ __forceinline__ bf16x8 pack8(float4 lo, float4 hi) {
  union { unsigned short s[8]; bf16x8 v; } u;
  u.s[0]=f2bfu(lo.x); u.s[1]=f2bfu(lo.y); u.s[2]=f2bfu(lo.z); u.s[3]=f2bfu(lo.w);
  u.s[4]=f2bfu(hi.x); u.s[5]=f2bfu(hi.y); u.s[6]=f2bfu(hi.z); u.s[7]=f2bfu(hi.w);
  return u.v;
}

// Swizzled LDS tile: 16B granules, granule index XORed with (row&7).
static __device__ __forceinline__ bf16x8 ldfrag(const __hip_bfloat16* buf, int gr, int row, int gi) {
  return *(const bf16x8*)&buf[(row*gr + (gi ^ (row & 7)))*8];
}
static __device__ __forceinline__ void stb(__hip_bfloat16* buf, int gr, int row, int col, float v) {
  int gi = col >> 3, off = col & 7;
  buf[(row*gr + (gi ^ (row & 7)))*8 + off] = f2bf(v);
}
static __device__ __forceinline__ float ldb(const __hip_bfloat16* buf, int gr, int row, int col) {
  int gi = col >> 3, off = col & 7;
  return bf2f(buf[(row*gr + (gi ^ (row & 7)))*8 + off]);
}

// Pre-swizzle weights into per-MFMA B-fragment order for 16x16x32:
// blob[((ct*nks + ks)*64 + lane)*8 + j] = W[ks*32 + (lane>>4)*8 + j][ct*16 + (lane&15)]
__global__ __launch_bounds__(256)
void prep_weights(const float* __restrict__ w1, const float* __restrict__ w2,
                  const float* __restrict__ a1w, const float* __restrict__ a2w,
                  __hip_bfloat16* __restrict__ blob) {
  int gid = blockIdx.x * 256 + threadIdx.x;           // 24576 total
  int layer = gid / 12288;
  int r = gid - layer * 12288;
  const float* W; int N, nks, g; __hip_bfloat16* dst;
  if (r < 2048)      { W = w1  + layer*NF*NF;  N = NF;  nks = 4; dst = blob + layer*LAYER_SZ + OW1; g = r; }
  else if (r < 4096) { W = w2  + layer*NF*NF;  N = NF;  nks = 4; dst = blob + layer*LAYER_SZ + OW2; g = r - 2048; }
  else if (r < 8192) { W = a1w + layer*NF2*NF; N = NF;  nks = 8; dst = blob + layer*LAYER_SZ + OA1; g = r - 4096; }
  else               { W = a2w + layer*NF*NF2; N = NF2; nks = 4; dst = blob + layer*LAYER_SZ + OA2; g = r - 8192; }
  int lane = g & 63;
  int ks = (g >> 6) % nks;
  int ct = g / (64 * nks);
  int k0 = ks * 32 + ((lane >> 4) << 3);
  int n  = ct * 16 + (lane & 15);
  __hip_bfloat16* o = dst + (size_t)((ct * nks + ks) * 64 + lane) * 8;
  #pragma unroll
  for (int j = 0; j < 8; ++j) o[j] = f2bf(W[(size_t)(k0 + j) * N + n]);
}

// Fused kernel: 3125 blocks x 512 thr (8 waves), 72 KB LDS, 2 blocks/CU.
// R2 post-mortem: still 8 dwords/lane of spill (WRITE 50 MB), VGPR pegged at
// the 128 cap. Phase A held w1f+w2f (32 regs) + 2 accs + n2sq[2][4] spanning
// both row-tiles. Fix: split Phase A into two passes (w1-only then w2-only),
// rt outer / c inner so only one 4-reg acc (+nq[4]) is live. Cost: vcur frags
// read twice (~3 us total) -- far cheaper than scratch round-trips.
__global__ __launch_bounds__(NTHR, 4)
void fused_equiv(const float* __restrict__ s_g, const float* __restrict__ v_g,
                 const __hip_bfloat16* __restrict__ blob,
                 const float* __restrict__ a1b, const float* __restrict__ a2b,
                 const float* __restrict__ out_w, const float* __restrict__ out_b,
                 float* __restrict__ sc) {
  __shared__ __hip_bfloat16 vcur[3*MT*NF];   // 24 KB, staged v, swizzled, gr=16
  __shared__ __hip_bfloat16 v1lds[3*MT*NF];  // 24 KB, v1 then gated v1
  __shared__ __hip_bfloat16 hbuf[MT*NF2];    // 16 KB, [s | n2], gr=32
  __shared__ __hip_bfloat16 h1[MT*NF];       // 8 KB, gr=16

  const int tid  = threadIdx.x;
  const int wave = tid >> 6;                 // 0..7
  const int lane = tid & 63;
  const int l15  = lane & 15;
  const int quad = lane >> 4;
  const int a0   = blockIdx.x * MT;
  const int col  = wave*16 + l15;            // output column this lane owns

  // ---- stage: global fp32 -> bf16 swizzled LDS (coalesced 32B/lane) ----
  {
    int row = tid >> 4, gi = tid & 15;       // s: 1 granule/thread (512 total)
    const float* sp = s_g + (size_t)a0*NF + row*NF + gi*8;
    float4 lo = *(const float4*)sp;
    float4 hi = *(const float4*)(sp + 4);
    *(bf16x8*)&hbuf[(row*32 + (gi ^ (row & 7)))*8] = pack8(lo, hi);
    #pragma unroll
    for (int u = 0; u < 3; ++u) {            // v: 3 granules/thread (1536 total)
      int g = tid + u*512;
      int R = g >> 4, gi2 = g & 15;          // R = atom*3 + c
      int at = R / 3, c = R - 3*at;
      const float* vp = v_g + (size_t)a0*3*NF + R*NF + gi2*8;
      float4 vlo = *(const float4*)vp;
      float4 vhi = *(const float4*)(vp + 4);
      *(bf16x8*)&vcur[((c*MT + at)*16 + (gi2 ^ (at & 7)))*8] = pack8(vlo, vhi);
    }
  }
  __syncthreads();

  const float b1a  = a1b[col];
  const float b1g  = a1b[NF + col];
  const float b2s  = a2b[col];
  const float b2g  = a2b[NF + col];
  const float b2s2 = a2b[2*NF + col];

  // ================= Layer 1 =================
  // ---- Phase A pass 1: v @ w1 -> v1lds (write-through) ----
  {
    const __hip_bfloat16* lb = blob;
    bf16x8 wf[4];
    #pragma unroll
    for (int ks = 0; ks < 4; ++ks)
      wf[ks] = *(const bf16x8*)&lb[OW1 + ((size_t)(wave*4 + ks)*64 + lane)*8];
    #pragma unroll
    for (int rt = 0; rt < 2; ++rt) {
      int row = rt*16 + l15;
      #pragma unroll
      for (int c = 0; c < 3; ++c) {
        const __hip_bfloat16* vp = vcur + c*MT*NF;
        f32x4 acc = {0.f,0.f,0.f,0.f};
        #pragma unroll
        for (int ks = 0; ks < 4; ++ks) {
          bf16x8 af = ldfrag(vp, 16, row, ks*4 + quad);
          acc = __builtin_amdgcn_mfma_f32_16x16x32_bf16(af, wf[ks], acc, 0, 0, 0);
        }
        #pragma unroll
        for (int i = 0; i < 4; ++i)
          stb(v1lds + c*MT*NF, 16, rt*16 + quad*4 + i, col, acc[i]);
      }
    }
  }
  // ---- Phase A pass 2: v @ w2 -> n2 (hbuf right half) ----
  {
    const __hip_bfloat16* lb = blob;
    bf16x8 wf[4];
    #pragma unroll
    for (int ks = 0; ks < 4; ++ks)
      wf[ks] = *(const bf16x8*)&lb[OW2 + ((size_t)(wave*4 + ks)*64 + lane)*8];
    #pragma unroll
    for (int rt = 0; rt < 2; ++rt) {
      int row = rt*16 + l15;
      float nq[4] = {0.f,0.f,0.f,0.f};
      #pragma unroll
      for (int c = 0; c < 3; ++c) {
        const __hip_bfloat16* vp = vcur + c*MT*NF;
        f32x4 acc = {0.f,0.f,0.f,0.f};
        #pragma unroll
        for (int ks = 0; ks < 4; ++ks) {
          bf16x8 af = ldfrag(vp, 16, row, ks*4 + quad);
          acc = __builtin_amdgcn_mfma_f32_16x16x32_bf16(af, wf[ks], acc, 0, 0, 0);
        }
        #pragma unroll
        for (int i = 0; i < 4; ++i) nq[i] += acc[i]*acc[i];
      }
      #pragma unroll
      for (int i = 0; i < 4; ++i)
        stb(hbuf, 32, rt*16 + quad*4 + i, NF + col, sqrtf(nq[i]));
    }
  }
  __syncthreads();

  // ---- Phase B: [s|n2] @ a1w + bias, silu -> h1 ----
  {
    const __hip_bfloat16* lb = blob;
    bf16x8 a1f[8];
    #pragma unroll
    for (int ks = 0; ks < 8; ++ks)
      a1f[ks] = *(const bf16x8*)&lb[OA1 + ((size_t)(wave*8 + ks)*64 + lane)*8];
    #pragma unroll
    for (int rt = 0; rt < 2; ++rt) {
      int row = rt*16 + l15;
      f32x4 acc = {0.f,0.f,0.f,0.f};
      #pragma unroll
      for (int ks = 0; ks < 8; ++ks) {
        bf16x8 af = ldfrag(hbuf, 32, row, ks*4 + quad);
        acc = __builtin_amdgcn_mfma_f32_16x16x32_bf16(af, a1f[ks], acc, 0, 0, 0);
      }
      #pragma unroll
      for (int i = 0; i < 4; ++i) {
        float x = acc[i] + b1a;
        stb(h1, 16, rt*16 + quad*4 + i, col, x / (1.0f + __expf(-x)));
      }
    }
  }
  __syncthreads();

  // ---- Phase C: h1 @ a2w -> s1 (hbuf) + gate * v1 (v1lds in place) ----
  {
    const __hip_bfloat16* lb = blob;
    bf16x8 asf[4], agf[4];
    #pragma unroll
    for (int ks = 0; ks < 4; ++ks) {
      asf[ks] = *(const bf16x8*)&lb[OA2 + ((size_t)(wave*4 + ks)*64 + lane)*8];
      agf[ks] = *(const bf16x8*)&lb[OA2 + ((size_t)((wave+8)*4 + ks)*64 + lane)*8];
    }
    #pragma unroll
    for (int rt = 0; rt < 2; ++rt) {
      int row = rt*16 + l15;
      f32x4 hs = {0.f,0.f,0.f,0.f}, hg = {0.f,0.f,0.f,0.f};
      #pragma unroll
      for (int ks = 0; ks < 4; ++ks) {
        bf16x8 af = ldfrag(h1, 16, row, ks*4 + quad);
        hs = __builtin_amdgcn_mfma_f32_16x16x32_bf16(af, asf[ks], hs, 0, 0, 0);
        hg = __builtin_amdgcn_mfma_f32_16x16x32_bf16(af, agf[ks], hg, 0, 0, 0);
      }
      #pragma unroll
      for (int i = 0; i < 4; ++i) {
        int r = rt*16 + quad*4 + i;
        stb(hbuf, 32, r, col, hs[i] + b2s);
        float g = hg[i] + b2g;
        stb(v1lds,           16, r, col, g * ldb(v1lds,           16, r, col));
        stb(v1lds +   MT*NF, 16, r, col, g * ldb(v1lds +   MT*NF, 16, r, col));
        stb(v1lds + 2*MT*NF, 16, r, col, g * ldb(v1lds + 2*MT*NF, 16, r, col));
      }
    }
  }
  __syncthreads();

  // ================= Layer 2 (v1/gate of last layer unused) =================
  // ---- Phase A': v' @ w2 -> n2 ----
  {
    const __hip_bfloat16* lb = blob + LAYER_SZ;
    bf16x8 wf[4];
    #pragma unroll
    for (int ks = 0; ks < 4; ++ks)
      wf[ks] = *(const bf16x8*)&lb[OW2 + ((size_t)(wave*4 + ks)*64 + lane)*8];
    #pragma unroll
    for (int rt = 0; rt < 2; ++rt) {
      int row = rt*16 + l15;
      float nq[4] = {0.f,0.f,0.f,0.f};
      #pragma unroll
      for (int c = 0; c < 3; ++c) {
        const __hip_bfloat16* vp = v1lds + c*MT*NF;
        f32x4 acc = {0.f,0.f,0.f,0.f};
        #pragma unroll
        for (int ks = 0; ks < 4; ++ks) {
          bf16x8 af = ldfrag(vp, 16, row, ks*4 + quad);
          acc = __builtin_amdgcn_mfma_f32_16x16x32_bf16(af, wf[ks], acc, 0, 0, 0);
        }
        #pragma unroll
        for (int i = 0; i < 4; ++i) nq[i] += acc[i]*acc[i];
      }
      #pragma unroll
      for (int i = 0; i < 4; ++i)
        stb(hbuf, 32, rt*16 + quad*4 + i, NF + col, sqrtf(nq[i]));
    }
  }
  __syncthreads();

  // ---- Phase B' ----
  {
    const __hip_bfloat16* lb = blob + LAYER_SZ;
    bf16x8 a1f[8];
    #pragma unroll
    for (int ks = 0; ks < 8; ++ks)
      a1f[ks] = *(const bf16x8*)&lb[OA1 + ((size_t)(wave*8 + ks)*64 + lane)*8];
    #pragma unroll
    for (int rt = 0; rt < 2; ++rt) {
      int row = rt*16 + l15;
      f32x4 acc = {0.f,0.f,0.f,0.f};
      #pragma unroll
      for (int ks = 0; ks < 8; ++ks) {
        bf16x8 af = ldfrag(hbuf, 32, row, ks*4 + quad);
        acc = __builtin_amdgcn_mfma_f32_16x16x32_bf16(af, a1f[ks], acc, 0, 0, 0);
      }
      #pragma unroll
      for (int i = 0; i < 4; ++i) {
        float x = acc[i] + b1g;
        stb(h1, 16, rt*16 + quad*4 + i, col, x / (1.0f + __expf(-x)));
      }
    }
  }
  __syncthreads();

  // ---- Phase C': s2 only -> hbuf s-half ----
  {
    const __hip_bfloat16* lb = blob + LAYER_SZ;
    bf16x8 asf[4];
    #pragma unroll
    for (int ks = 0; ks < 4; ++ks)
      asf[ks] = *(const bf16x8*)&lb[OA2 + ((size_t)(wave*4 + ks)*64 + lane)*8];
    #pragma unroll
    for (int rt = 0; rt < 2; ++rt) {
      int row = rt*16 + l15;
      f32x4 hs = {0.f,0.f,0.f,0.f};
      #pragma unroll
      for (int ks = 0; ks < 4; ++ks) {
        bf16x8 af = ldfrag(h1, 16, row, ks*4 + quad);
        hs = __builtin_amdgcn_mfma_f32_16x16x32_bf16(af, asf[ks], hs, 0, 0, 0);
      }
      #pragma unroll
      for (int i = 0; i < 4; ++i)
        stb(hbuf, 32, rt*16 + quad*4 + i, col, hs[i] + b2s2);
    }
  }
  __syncthreads();

  // ---- head: sc[atom] = dot(s2, out_w) + out_b ----
  {
    int a   = tid >> 4;        // 32 atoms x 16 threads
    int sub = tid & 15;
    float p = 0.f;
    #pragma unroll
    for (int j = 0; j < 8; ++j) {
      int f = sub*8 + j;
      p += ldb(hbuf, 32, a, f) * out_w[f];
    }
    p += __shfl_down(p, 8, 16);
    p += __shfl_down(p, 4, 16);
    p += __shfl_down(p, 2, 16);
    p += __shfl_down(p, 1, 16);
    if (sub == 0) sc[a0 + a] = p + out_b[0];
  }
}

// Stage 1: partials over 16 aligned chunks per graph (2048 blocks, float4 loads)
#define CHUNK 6256   // 16B-aligned chunk (6256*4 bytes); last chunk = 6160
__global__ __launch_bounds__(256)
void reduce_partial(const float* __restrict__ mask, const float* __restrict__ sc,
                    float* __restrict__ partial) {
  int b  = blockIdx.x >> 4;
  int ch = blockIdx.x & 15;
  int n0 = ch * CHUNK;
  int n1 = n0 + CHUNK; if (n1 > NATOMS) n1 = NATOMS;
  const float4* m4 = (const float4*)(mask + (size_t)b * NATOMS + n0);
  const float4* s4 = (const float4*)(sc + n0);
  int nq = (n1 - n0) >> 2;
  float acc = 0.f;
  for (int i = threadIdx.x; i < nq; i += 256) {
    float4 m = m4[i], s = s4[i];
    acc += m.x*s.x + m.y*s.y + m.z*s.z + m.w*s.w;
  }
  #pragma unroll
  for (int d = 32; d > 0; d >>= 1) acc += __shfl_down(acc, d, 64);
  __shared__ float red[4];
  if ((threadIdx.x & 63) == 0) red[threadIdx.x >> 6] = acc;
  __syncthreads();
  if (threadIdx.x == 0) partial[blockIdx.x] = red[0] + red[1] + red[2] + red[3];
}

__global__ void reduce_final(const float* __restrict__ partial, float* __restrict__ out) {
  int b = threadIdx.x;
  if (b < NGRAPH) {
    float s = 0.f;
    #pragma unroll
    for (int k = 0; k < 16; ++k) s += partial[b*16 + k];
    out[b] = s;
  }
}

extern "C" void kernel_launch(void* const* d_in, const int* in_sizes, int n_in,
                              void* d_out, int out_size, void* d_ws, size_t ws_size,
                              hipStream_t stream) {
  const float* s    = (const float*)d_in[0];
  const float* v    = (const float*)d_in[1];
  // d_in[2] = r, unused
  const float* mask = (const float*)d_in[3];
  const float* w1   = (const float*)d_in[4];
  const float* w2   = (const float*)d_in[5];
  const float* a1w  = (const float*)d_in[6];
  const float* a1b  = (const float*)d_in[7];
  const float* a2w  = (const float*)d_in[8];
  const float* a2b  = (const float*)d_in[9];
  const float* outw = (const float*)d_in[10];
  const float* outb = (const float*)d_in[11];

  char* ws = (char*)d_ws;
  __hip_bfloat16* blob = (__hip_bfloat16*)ws;                      // 384 KB
  float* sc      = (float*)(ws + (size_t)2*LAYER_SZ*2);            // 400 KB
  float* partial = (float*)(ws + (size_t)2*LAYER_SZ*2 + NATOMS*4); // 8 KB

  prep_weights<<<96, 256, 0, stream>>>(w1, w2, a1w, a2w, blob);
  fused_equiv<<<NBLK, NTHR, 0, stream>>>(s, v, blob, a1b, a2b, outw, outb, sc);
  reduce_partial<<<NGRAPH*16, 256, 0, stream>>>(mask, sc, partial);
  reduce_final<<<1, 128, 0, stream>>>(partial, (float*)d_out);
}

// Round 4
// 359.103 us; speedup vs baseline: 1.2333x; 1.0077x over previous
//
#include <hip/hip_runtime.h>
#include <hip/hip_bf16.h>

#define NF 128
#define NF2 256
#define NATOMS 100000
#define NGRAPH 128

#define MT 32
#define NBLK (NATOMS/MT)      // 3125
#define NTHR 512              // 8 waves

// blob layout per layer (bf16 elems): frags for 16x16x32 MFMA B-operand
#define OW1 0                 // 8ct x 4ks
#define OW2 16384
#define OA1 32768             // 8ct x 8ks
#define OA2 65536             // 16ct x 4ks (ct0-7 = s-half, ct8-15 = gate)
#define LAYER_SZ 98304

typedef __attribute__((ext_vector_type(8))) short bf16x8;
typedef __attribute__((ext_vector_type(4))) short bf16x4;
typedef __attribute__((ext_vector_type(4))) float f32x4;

static __device__ __forceinline__ float bf2f(__hip_bfloat16 x) { return __bfloat162float(x); }
static __device__ __forceinline__ __hip_bfloat16 f2bf(float x) { return __float2bfloat16(x); }
static __device__ __forceinline__ unsigned short f2bfu(float x) {
  __hip_bfloat16 h = __float2bfloat16(x);
  return *(unsigned short*)&h;
}
static __device__ __forceinline__ bf16x8 pack8(float4 lo, float4 hi) {
  union { unsigned short s[8]; bf16x8 v; } u;
  u.s[0]=f2bfu(lo.x); u.s[1]=f2bfu(lo.y); u.s[2]=f2bfu(lo.z); u.s[3]=f2bfu(lo.w);
  u.s[4]=f2bfu(hi.x); u.s[5]=f2bfu(hi.y); u.s[6]=f2bfu(hi.z); u.s[7]=f2bfu(hi.w);
  return u.v;
}
static __device__ __forceinline__ bf16x4 pack4f(f32x4 a) {
  union { unsigned short s[4]; bf16x4 v; } u;
  u.s[0]=f2bfu(a[0]); u.s[1]=f2bfu(a[1]); u.s[2]=f2bfu(a[2]); u.s[3]=f2bfu(a[3]);
  return u.v;
}
static __device__ __forceinline__ float bfs2f(short s) {
  __hip_bfloat16 h; *(short*)&h = s; return __bfloat162float(h);
}

// Swizzled LDS tile: 16B granules, granule index XORed with (row&7).
static __device__ __forceinline__ bf16x8 ldfrag(const __hip_bfloat16* buf, int gr, int row, int gi) {
  return *(const bf16x8*)&buf[(row*gr + (gi ^ (row & 7)))*8];
}
// Packed 4-elem (8B) store/load at col base multiple of 4 (off 0 or 4 in granule).
static __device__ __forceinline__ void stq(__hip_bfloat16* buf, int gr, int row, int colb, bf16x4 v) {
  int gi = colb >> 3, off = colb & 7;
  *(bf16x4*)&buf[(row*gr + (gi ^ (row & 7)))*8 + off] = v;
}
static __device__ __forceinline__ bf16x4 ldq(const __hip_bfloat16* buf, int gr, int row, int colb) {
  int gi = colb >> 3, off = colb & 7;
  return *(const bf16x4*)&buf[(row*gr + (gi ^ (row & 7)))*8 + off];
}
static __device__ __forceinline__ float ldb(const __hip_bfloat16* buf, int gr, int row, int col) {
  int gi = col >> 3, off = col & 7;
  return bf2f(buf[(row*gr + (gi ^ (row & 7)))*8 + off]);
}

// Pre-swizzle weights into per-MFMA B-fragment order for 16x16x32:
// blob[((ct*nks + ks)*64 + lane)*8 + j] = W[ks*32 + (lane>>4)*8 + j][ct*16 + (lane&15)]
__global__ __launch_bounds__(256)
void prep_weights(const float* __restrict__ w1, const float* __restrict__ w2,
                  const float* __restrict__ a1w, const float* __restrict__ a2w,
                  __hip_bfloat16* __restrict__ blob) {
  int gid = blockIdx.x * 256 + threadIdx.x;           // 24576 total
  int layer = gid / 12288;
  int r = gid - layer * 12288;
  const float* W; int N, nks, g; __hip_bfloat16* dst;
  if (r < 2048)      { W = w1  + layer*NF*NF;  N = NF;  nks = 4; dst = blob + layer*LAYER_SZ + OW1; g = r; }
  else if (r < 4096) { W = w2  + layer*NF*NF;  N = NF;  nks = 4; dst = blob + layer*LAYER_SZ + OW2; g = r - 2048; }
  else if (r < 8192) { W = a1w + layer*NF2*NF; N = NF;  nks = 8; dst = blob + layer*LAYER_SZ + OA1; g = r - 4096; }
  else               { W = a2w + layer*NF*NF2; N = NF2; nks = 4; dst = blob + layer*LAYER_SZ + OA2; g = r - 8192; }
  int lane = g & 63;
  int ks = (g >> 6) % nks;
  int ct = g / (64 * nks);
  int k0 = ks * 32 + ((lane >> 4) << 3);
  int n  = ct * 16 + (lane & 15);
  __hip_bfloat16* o = dst + (size_t)((ct * nks + ks) * 64 + lane) * 8;
  #pragma unroll
  for (int j = 0; j < 8; ++j) o[j] = f2bf(W[(size_t)(k0 + j) * N + n]);
}

// Fused kernel: 3125 blocks x 512 thr (8 waves), 72 KB LDS, 2 blocks/CU.
// R3 post-mortem: scalar ds_write_b16/ds_read_u16 inter-phase traffic (~128
// scalar LDS ops/wave + swizzle VALU + ~8-way write conflicts) dominated.
// Fix: OPERAND-SWAPPED MFMA — mfma(Wfrag, vfrag) computes (v@W)^T, so each
// lane's f32x4 holds 4 CONSECUTIVE FEATURES of one atom -> packed b64 LDS
// writes (stq), b64 gate read-modify-write (ldq/stq). All buffers stay
// [atom][feature] row-major, matching the A-fragment reads (ldfrag).
__global__ __launch_bounds__(NTHR, 4)
void fused_equiv(const float* __restrict__ s_g, const float* __restrict__ v_g,
                 const __hip_bfloat16* __restrict__ blob,
                 const float* __restrict__ a1b, const float* __restrict__ a2b,
                 const float* __restrict__ out_w, const float* __restrict__ out_b,
                 float* __restrict__ sc) {
  __shared__ __hip_bfloat16 vcur[3*MT*NF];   // 24 KB, staged v, swizzled, gr=16
  __shared__ __hip_bfloat16 v1lds[3*MT*NF];  // 24 KB, v1 then gated v1
  __shared__ __hip_bfloat16 hbuf[MT*NF2];    // 16 KB, [s | n2], gr=32
  __shared__ __hip_bfloat16 h1[MT*NF];       // 8 KB, gr=16

  const int tid  = threadIdx.x;
  const int wave = tid >> 6;                 // 0..7
  const int lane = tid & 63;
  const int l15  = lane & 15;
  const int quad = lane >> 4;
  const int a0   = blockIdx.x * MT;
  const int fb   = wave*16 + quad*4;         // feature base this lane owns (4 consecutive)

  // ---- stage: global fp32 -> bf16 swizzled LDS (coalesced 32B/lane) ----
  {
    int row = tid >> 4, gi = tid & 15;       // s: 1 granule/thread (512 total)
    const float* sp = s_g + (size_t)a0*NF + row*NF + gi*8;
    float4 lo = *(const float4*)sp;
    float4 hi = *(const float4*)(sp + 4);
    *(bf16x8*)&hbuf[(row*32 + (gi ^ (row & 7)))*8] = pack8(lo, hi);
    #pragma unroll
    for (int u = 0; u < 3; ++u) {            // v: 3 granules/thread (1536 total)
      int g = tid + u*512;
      int R = g >> 4, gi2 = g & 15;          // R = atom*3 + c
      int at = R / 3, c = R - 3*at;
      const float* vp = v_g + (size_t)a0*3*NF + R*NF + gi2*8;
      float4 vlo = *(const float4*)vp;
      float4 vhi = *(const float4*)(vp + 4);
      *(bf16x8*)&vcur[((c*MT + at)*16 + (gi2 ^ (at & 7)))*8] = pack8(vlo, vhi);
    }
  }
  __syncthreads();

  const f32x4 b1a4  = *(const f32x4*)&a1b[fb];          // layer1 silu bias
  const f32x4 b1g4  = *(const f32x4*)&a1b[NF + fb];     // layer2 silu bias
  const f32x4 b2s4  = *(const f32x4*)&a2b[fb];          // layer1 s bias
  const f32x4 b2g4  = *(const f32x4*)&a2b[NF + fb];     // layer1 gate bias
  const f32x4 b2s24 = *(const f32x4*)&a2b[2*NF + fb];   // layer2 s bias

  // ================= Layer 1 =================
  // ---- Phase A1: (v @ w1)^T -> v1lds, packed b64 writes ----
  {
    const __hip_bfloat16* lb = blob;
    bf16x8 wf[4];
    #pragma unroll
    for (int ks = 0; ks < 4; ++ks)
      wf[ks] = *(const bf16x8*)&lb[OW1 + ((size_t)(wave*4 + ks)*64 + lane)*8];
    #pragma unroll
    for (int rt = 0; rt < 2; ++rt) {
      int arow = rt*16 + l15;
      #pragma unroll
      for (int c = 0; c < 3; ++c) {
        f32x4 acc = {0.f,0.f,0.f,0.f};
        #pragma unroll
        for (int ks = 0; ks < 4; ++ks) {
          bf16x8 af = ldfrag(vcur + c*MT*NF, 16, arow, ks*4 + quad);
          acc = __builtin_amdgcn_mfma_f32_16x16x32_bf16(wf[ks], af, acc, 0, 0, 0);
        }
        stq(v1lds + c*MT*NF, 16, arow, fb, pack4f(acc));
      }
    }
  }
  // ---- Phase A2: (v @ w2)^T -> n2 (hbuf right half) ----
  {
    const __hip_bfloat16* lb = blob;
    bf16x8 wf[4];
    #pragma unroll
    for (int ks = 0; ks < 4; ++ks)
      wf[ks] = *(const bf16x8*)&lb[OW2 + ((size_t)(wave*4 + ks)*64 + lane)*8];
    #pragma unroll
    for (int rt = 0; rt < 2; ++rt) {
      int arow = rt*16 + l15;
      f32x4 nq = {0.f,0.f,0.f,0.f};
      #pragma unroll
      for (int c = 0; c < 3; ++c) {
        f32x4 acc = {0.f,0.f,0.f,0.f};
        #pragma unroll
        for (int ks = 0; ks < 4; ++ks) {
          bf16x8 af = ldfrag(vcur + c*MT*NF, 16, arow, ks*4 + quad);
          acc = __builtin_amdgcn_mfma_f32_16x16x32_bf16(wf[ks], af, acc, 0, 0, 0);
        }
        #pragma unroll
        for (int i = 0; i < 4; ++i) nq[i] += acc[i]*acc[i];
      }
      f32x4 nv;
      #pragma unroll
      for (int i = 0; i < 4; ++i) nv[i] = sqrtf(nq[i]);
      stq(hbuf, 32, arow, NF + fb, pack4f(nv));
    }
  }
  __syncthreads();

  // ---- Phase B: ([s|n2] @ a1w)^T + bias, silu -> h1 ----
  {
    const __hip_bfloat16* lb = blob;
    bf16x8 a1f[8];
    #pragma unroll
    for (int ks = 0; ks < 8; ++ks)
      a1f[ks] = *(const bf16x8*)&lb[OA1 + ((size_t)(wave*8 + ks)*64 + lane)*8];
    #pragma unroll
    for (int rt = 0; rt < 2; ++rt) {
      int arow = rt*16 + l15;
      f32x4 acc = {0.f,0.f,0.f,0.f};
      #pragma unroll
      for (int ks = 0; ks < 8; ++ks) {
        bf16x8 af = ldfrag(hbuf, 32, arow, ks*4 + quad);
        acc = __builtin_amdgcn_mfma_f32_16x16x32_bf16(a1f[ks], af, acc, 0, 0, 0);
      }
      f32x4 h;
      #pragma unroll
      for (int i = 0; i < 4; ++i) {
        float x = acc[i] + b1a4[i];
        h[i] = x / (1.0f + __expf(-x));
      }
      stq(h1, 16, arow, fb, pack4f(h));
    }
  }
  __syncthreads();

  // ---- Phase C: (h1 @ a2w)^T -> s1 (hbuf) + gate * v1 (v1lds, b64 RMW) ----
  {
    const __hip_bfloat16* lb = blob;
    bf16x8 asf[4], agf[4];
    #pragma unroll
    for (int ks = 0; ks < 4; ++ks) {
      asf[ks] = *(const bf16x8*)&lb[OA2 + ((size_t)(wave*4 + ks)*64 + lane)*8];
      agf[ks] = *(const bf16x8*)&lb[OA2 + ((size_t)((wave+8)*4 + ks)*64 + lane)*8];
    }
    #pragma unroll
    for (int rt = 0; rt < 2; ++rt) {
      int arow = rt*16 + l15;
      f32x4 hs = {0.f,0.f,0.f,0.f}, hg = {0.f,0.f,0.f,0.f};
      #pragma unroll
      for (int ks = 0; ks < 4; ++ks) {
        bf16x8 af = ldfrag(h1, 16, arow, ks*4 + quad);
        hs = __builtin_amdgcn_mfma_f32_16x16x32_bf16(asf[ks], af, hs, 0, 0, 0);
        hg = __builtin_amdgcn_mfma_f32_16x16x32_bf16(agf[ks], af, hg, 0, 0, 0);
      }
      f32x4 sv, g;
      #pragma unroll
      for (int i = 0; i < 4; ++i) { sv[i] = hs[i] + b2s4[i]; g[i] = hg[i] + b2g4[i]; }
      stq(hbuf, 32, arow, fb, pack4f(sv));
      #pragma unroll
      for (int c = 0; c < 3; ++c) {
        bf16x4 vv = ldq(v1lds + c*MT*NF, 16, arow, fb);
        f32x4 gv;
        #pragma unroll
        for (int i = 0; i < 4; ++i) gv[i] = g[i] * bfs2f(vv[i]);
        stq(v1lds + c*MT*NF, 16, arow, fb, pack4f(gv));
      }
    }
  }
  __syncthreads();

  // ================= Layer 2 =================
  // ---- Phase A': (v' @ w2)^T -> n2 ----
  {
    const __hip_bfloat16* lb = blob + LAYER_SZ;
    bf16x8 wf[4];
    #pragma unroll
    for (int ks = 0; ks < 4; ++ks)
      wf[ks] = *(const bf16x8*)&lb[OW2 + ((size_t)(wave*4 + ks)*64 + lane)*8];
    #pragma unroll
    for (int rt = 0; rt < 2; ++rt) {
      int arow = rt*16 + l15;
      f32x4 nq = {0.f,0.f,0.f,0.f};
      #pragma unroll
      for (int c = 0; c < 3; ++c) {
        f32x4 acc = {0.f,0.f,0.f,0.f};
        #pragma unroll
        for (int ks = 0; ks < 4; ++ks) {
          bf16x8 af = ldfrag(v1lds + c*MT*NF, 16, arow, ks*4 + quad);
          acc = __builtin_amdgcn_mfma_f32_16x16x32_bf16(wf[ks], af, acc, 0, 0, 0);
        }
        #pragma unroll
        for (int i = 0; i < 4; ++i) nq[i] += acc[i]*acc[i];
      }
      f32x4 nv;
      #pragma unroll
      for (int i = 0; i < 4; ++i) nv[i] = sqrtf(nq[i]);
      stq(hbuf, 32, arow, NF + fb, pack4f(nv));
    }
  }
  __syncthreads();

  // ---- Phase B' ----
  {
    const __hip_bfloat16* lb = blob + LAYER_SZ;
    bf16x8 a1f[8];
    #pragma unroll
    for (int ks = 0; ks < 8; ++ks)
      a1f[ks] = *(const bf16x8*)&lb[OA1 + ((size_t)(wave*8 + ks)*64 + lane)*8];
    #pragma unroll
    for (int rt = 0; rt < 2; ++rt) {
      int arow = rt*16 + l15;
      f32x4 acc = {0.f,0.f,0.f,0.f};
      #pragma unroll
      for (int ks = 0; ks < 8; ++ks) {
        bf16x8 af = ldfrag(hbuf, 32, arow, ks*4 + quad);
        acc = __builtin_amdgcn_mfma_f32_16x16x32_bf16(a1f[ks], af, acc, 0, 0, 0);
      }
      f32x4 h;
      #pragma unroll
      for (int i = 0; i < 4; ++i) {
        float x = acc[i] + b1g4[i];
        h[i] = x / (1.0f + __expf(-x));
      }
      stq(h1, 16, arow, fb, pack4f(h));
    }
  }
  __syncthreads();

  // ---- Phase C': s2 only -> hbuf s-half ----
  {
    const __hip_bfloat16* lb = blob + LAYER_SZ;
    bf16x8 asf[4];
    #pragma unroll
    for (int ks = 0; ks < 4; ++ks)
      asf[ks] = *(const bf16x8*)&lb[OA2 + ((size_t)(wave*4 + ks)*64 + lane)*8];
    #pragma unroll
    for (int rt = 0; rt < 2; ++rt) {
      int arow = rt*16 + l15;
      f32x4 hs = {0.f,0.f,0.f,0.f};
      #pragma unroll
      for (int ks = 0; ks < 4; ++ks) {
        bf16x8 af = ldfrag(h1, 16, arow, ks*4 + quad);
        hs = __builtin_amdgcn_mfma_f32_16x16x32_bf16(asf[ks], af, hs, 0, 0, 0);
      }
      f32x4 sv;
      #pragma unroll
      for (int i = 0; i < 4; ++i) sv[i] = hs[i] + b2s24[i];
      stq(hbuf, 32, arow, fb, pack4f(sv));
    }
  }
  __syncthreads();

  // ---- head: sc[atom] = dot(s2, out_w) + out_b ----
  {
    int a   = tid >> 4;        // 32 atoms x 16 threads
    int sub = tid & 15;
    float p = 0.f;
    #pragma unroll
    for (int j = 0; j < 8; ++j) {
      int f = sub*8 + j;
      p += ldb(hbuf, 32, a, f) * out_w[f];
    }
    p += __shfl_down(p, 8, 16);
    p += __shfl_down(p, 4, 16);
    p += __shfl_down(p, 2, 16);
    p += __shfl_down(p, 1, 16);
    if (sub == 0) sc[a0 + a] = p + out_b[0];
  }
}

// Stage 1: partials over 16 aligned chunks per graph (2048 blocks, float4 loads)
#define CHUNK 6256   // 16B-aligned chunk (6256*4 bytes); last chunk = 6160
__global__ __launch_bounds__(256)
void reduce_partial(const float* __restrict__ mask, const float* __restrict__ sc,
                    float* __restrict__ partial) {
  int b  = blockIdx.x >> 4;
  int ch = blockIdx.x & 15;
  int n0 = ch * CHUNK;
  int n1 = n0 + CHUNK; if (n1 > NATOMS) n1 = NATOMS;
  const float4* m4 = (const float4*)(mask + (size_t)b * NATOMS + n0);
  const float4* s4 = (const float4*)(sc + n0);
  int nq = (n1 - n0) >> 2;
  float acc = 0.f;
  for (int i = threadIdx.x; i < nq; i += 256) {
    float4 m = m4[i], s = s4[i];
    acc += m.x*s.x + m.y*s.y + m.z*s.z + m.w*s.w;
  }
  #pragma unroll
  for (int d = 32; d > 0; d >>= 1) acc += __shfl_down(acc, d, 64);
  __shared__ float red[4];
  if ((threadIdx.x & 63) == 0) red[threadIdx.x >> 6] = acc;
  __syncthreads();
  if (threadIdx.x == 0) partial[blockIdx.x] = red[0] + red[1] + red[2] + red[3];
}

__global__ void reduce_final(const float* __restrict__ partial, float* __restrict__ out) {
  int b = threadIdx.x;
  if (b < NGRAPH) {
    float s = 0.f;
    #pragma unroll
    for (int k = 0; k < 16; ++k) s += partial[b*16 + k];
    out[b] = s;
  }
}

extern "C" void kernel_launch(void* const* d_in, const int* in_sizes, int n_in,
                              void* d_out, int out_size, void* d_ws, size_t ws_size,
                              hipStream_t stream) {
  const float* s    = (const float*)d_in[0];
  const float* v    = (const float*)d_in[1];
  // d_in[2] = r, unused
  const float* mask = (const float*)d_in[3];
  const float* w1   = (const float*)d_in[4];
  const float* w2   = (const float*)d_in[5];
  const float* a1w  = (const float*)d_in[6];
  const float* a1b  = (const float*)d_in[7];
  const float* a2w  = (const float*)d_in[8];
  const float* a2b  = (const float*)d_in[9];
  const float* outw = (const float*)d_in[10];
  const float* outb = (const float*)d_in[11];

  char* ws = (char*)d_ws;
  __hip_bfloat16* blob = (__hip_bfloat16*)ws;                      // 384 KB
  float* sc      = (float*)(ws + (size_t)2*LAYER_SZ*2);            // 400 KB
  float* partial = (float*)(ws + (size_t)2*LAYER_SZ*2 + NATOMS*4); // 8 KB

  prep_weights<<<96, 256, 0, stream>>>(w1, w2, a1w, a2w, blob);
  fused_equiv<<<NBLK, NTHR, 0, stream>>>(s, v, blob, a1b, a2b, outw, outb, sc);
  reduce_partial<<<NGRAPH*16, 256, 0, stream>>>(mask, sc, partial);
  reduce_final<<<1, 128, 0, stream>>>(partial, (float*)d_out);
}